// Round 4
// baseline (568.503 us; speedup 1.0000x reference)
//
#include <hip/hip_runtime.h>

typedef unsigned short u16;
typedef __attribute__((ext_vector_type(8))) short short8;
typedef __attribute__((ext_vector_type(4))) float f32x4;
typedef __attribute__((ext_vector_type(4))) unsigned short u16x4;

// ---------- bf16 helpers (OCP bf16 = raw upper 16 bits of fp32, RNE) ----------
__device__ __forceinline__ float bf2f(u16 h){
  unsigned u = ((unsigned)h) << 16; float f; __builtin_memcpy(&f, &u, 4); return f;
}
__device__ __forceinline__ u16 f2bf(float f){
  unsigned u; __builtin_memcpy(&u, &f, 4);
  unsigned r = u + 0x7fffu + ((u >> 16) & 1u);
  return (u16)(r >> 16);
}

// ---------- async global->LDS (16B per lane, wave-uniform LDS base) ----------
__device__ __forceinline__ void glds16(const u16* g, u16* l){
  __builtin_amdgcn_global_load_lds(
      (const __attribute__((address_space(1))) unsigned int*)(const void*)g,
      (__attribute__((address_space(3))) unsigned int*)(void*)l, 16, 0, 0);
}

// ---------- fp32 -> bf16 conversion (x) ----------
__global__ __launch_bounds__(256) void cvt_f32_bf16(const float* __restrict__ src,
                                                    u16* __restrict__ dst, int n4){
  int i = blockIdx.x * 256 + threadIdx.x;
  if (i >= n4) return;
  float4 f = ((const float4*)src)[i];
  u16x4 o; o.x = f2bf(f.x); o.y = f2bf(f.y); o.z = f2bf(f.z); o.w = f2bf(f.w);
  ((u16x4*)dst)[i] = o;
}

// ---------- fused weight conversion: Wq|Wk|Wv|Wo -> contiguous bf16 ----------
__global__ __launch_bounds__(256) void cvt_w4(const float* __restrict__ w0,
    const float* __restrict__ w1, const float* __restrict__ w2,
    const float* __restrict__ w3, u16* __restrict__ dst){
  int blk = blockIdx.x;                    // 16384 blocks, 4096 per matrix
  int which = blk >> 12;
  const float* src = (which == 0) ? w0 : (which == 1) ? w1 : (which == 2) ? w2 : w3;
  int i = (blk & 4095) * 256 + threadIdx.x;
  float4 f = ((const float4*)src)[i];
  u16x4 o; o.x = f2bf(f.x); o.y = f2bf(f.y); o.z = f2bf(f.z); o.w = f2bf(f.w);
  ((u16x4*)(dst + (size_t)which * 4194304))[i] = o;
}

// ---------- GEMM C[M,N] = A[M,K] @ B[N,K]^T  (both bf16, K=2048, BK=64) ----------
// mode 0: N=6144 (Wq|Wk|Wv); Q,K scatter into [B,H,S,DK], V into [B,H,DK,S] (transposed!)
// mode 1: N=2048 (Wo), write fp32 out + bias
// BK=64: 32 MFMA per barrier-pair (2x m97 density), 32 KB LDS.
// LDS layout: row-major [128][64], 8 chunks of 8 u16 per row, phys_chunk = log ^ (row&7).
__global__ __launch_bounds__(256) void gemm_bt(
    const u16* __restrict__ A, const u16* __restrict__ Bm, int mode,
    u16* __restrict__ qws, u16* __restrict__ kws, u16* __restrict__ vws,
    const float* __restrict__ bq, const float* __restrict__ bk, const float* __restrict__ bv,
    float* __restrict__ outf, const float* __restrict__ bo)
{
  const int K = 2048;
  __shared__ __attribute__((aligned(16))) u16 As[128 * 64];
  __shared__ __attribute__((aligned(16))) u16 Bs[128 * 64];

  int tid = threadIdx.x, wave = tid >> 6, lane = tid & 63;
  int quad = lane >> 4, l15 = lane & 15;
  int wm = wave >> 1, wn = wave & 1;

  // staging: round r (0..3), thread tid covers row = r*32 + (tid>>3), phys chunk tid&7
  int rr = tid >> 3, cp = tid & 7;
  int cl = cp ^ (rr & 7);                  // logical chunk (row&7 == rr&7 for all rounds)
  size_t rowA0 = (size_t)blockIdx.y * 128;
  size_t rowB0 = (size_t)blockIdx.x * 128;
  const u16* gA[4]; const u16* gB[4]; u16* lA[4]; u16* lB[4];
  #pragma unroll
  for (int r = 0; r < 4; r++){
    gA[r] = A  + (rowA0 + r * 32 + rr) * K + cl * 8;
    gB[r] = Bm + (rowB0 + r * 32 + rr) * K + cl * 8;
    lA[r] = As + (size_t)(r * 256 + wave * 64) * 8;
    lB[r] = Bs + (size_t)(r * 256 + wave * 64) * 8;
  }

  f32x4 acc[4][4];
  #pragma unroll
  for (int i = 0; i < 4; i++)
    #pragma unroll
    for (int j = 0; j < 4; j++) acc[i][j] = f32x4{0.f, 0.f, 0.f, 0.f};

  // fragment read offsets (kc=0); kc=1 is aoff ^ 32 (phys chunk bit2 flip)
  int aoff[4], boff[4];
  #pragma unroll
  for (int t = 0; t < 4; t++){
    int ra = wm * 64 + t * 16 + l15;
    aoff[t] = ra * 64 + ((quad ^ (l15 & 7)) * 8);
    int rb = wn * 64 + t * 16 + l15;
    boff[t] = rb * 64 + ((quad ^ (l15 & 7)) * 8);
  }

  for (int k0 = 0; k0 < K; k0 += 64){
    __syncthreads();
    #pragma unroll
    for (int r = 0; r < 4; r++){ glds16(gA[r], lA[r]); glds16(gB[r], lB[r]); }
    #pragma unroll
    for (int r = 0; r < 4; r++){ gA[r] += 64; gB[r] += 64; }
    __syncthreads();
    #pragma unroll
    for (int kc = 0; kc < 2; kc++){
      int x = kc * 32;
      short8 af[4], bfr[4];
      #pragma unroll
      for (int t = 0; t < 4; t++){
        af[t]  = *(const short8*)(As + (aoff[t] ^ x));
        bfr[t] = *(const short8*)(Bs + (boff[t] ^ x));
      }
      #pragma unroll
      for (int i = 0; i < 4; i++)
        #pragma unroll
        for (int j = 0; j < 4; j++)
          acc[i][j] = __builtin_amdgcn_mfma_f32_16x16x32_bf16(af[i], bfr[j], acc[i][j], 0, 0, 0);
    }
  }

  // C layout per 16x16 tile: row m = quad*4 + reg, col n = l15   [verified m89]
  if (mode == 0){
    int col0 = (int)rowB0;
    int mat = col0 >> 11;
    int cm  = col0 & 2047;
    const float* bias = (mat == 0) ? bq : (mat == 1) ? bk : bv;
    int b  = (int)(rowA0 >> 11);
    int s0 = (int)(rowA0 & 2047);
    int h  = cm >> 7;
    size_t base = ((size_t)(b * 16 + h)) * 2048 * 128;
    if (mat == 2){
      // V stored TRANSPOSED: [B,H,DK,S]
      #pragma unroll
      for (int j = 0; j < 4; j++){
        int d = wn * 64 + j * 16 + l15;
        float bv_ = bias[cm + d];
        #pragma unroll
        for (int i = 0; i < 4; i++){
          int srow = s0 + wm * 64 + i * 16 + quad * 4;
          u16x4 pk;
          #pragma unroll
          for (int r = 0; r < 4; r++) pk[r] = f2bf(acc[i][j][r] + bv_);
          *(u16x4*)(vws + base + (size_t)d * 2048 + srow) = pk;
        }
      }
    } else {
      u16* dst = (mat == 0) ? qws : kws;
      #pragma unroll
      for (int j = 0; j < 4; j++){
        int d = wn * 64 + j * 16 + l15;
        float bv_ = bias[cm + d];
        #pragma unroll
        for (int i = 0; i < 4; i++){
          int srow = s0 + wm * 64 + i * 16 + quad * 4;
          #pragma unroll
          for (int r = 0; r < 4; r++)
            dst[base + (size_t)(srow + r) * 128 + d] = f2bf(acc[i][j][r] + bv_);
        }
      }
    }
  } else {
    int col0 = (int)rowB0;
    #pragma unroll
    for (int j = 0; j < 4; j++){
      int c = col0 + wn * 64 + j * 16 + l15;
      float bo_ = bo[c];
      #pragma unroll
      for (int i = 0; i < 4; i++){
        int rg = (int)rowA0 + wm * 64 + i * 16 + quad * 4;
        #pragma unroll
        for (int r = 0; r < 4; r++)
          outf[(size_t)(rg + r) * 2048 + c] = acc[i][j][r] + bo_;
      }
    }
  }
}

// ---------- RoPE in-place on Q,K  ([B*H, S, 128] bf16) ----------
__global__ __launch_bounds__(256) void rope_qk(u16* __restrict__ q, u16* __restrict__ k){
  int tid = blockIdx.x * 256 + threadIdx.x;
  int j  = tid & 63;
  int s  = (tid >> 6) & 2047;
  int bh = tid >> 17;
  size_t base = ((size_t)bh * 2048 + (size_t)s) * 128;
  float inv = __expf((float)j * -0.14391156831212788f);
  float th = (float)s * inv;
  float sn, cs; __sincosf(th, &sn, &cs);
  float a = bf2f(q[base + j]), b = bf2f(q[base + j + 64]);
  q[base + j]      = f2bf(a * cs - b * sn);
  q[base + j + 64] = f2bf(b * cs + a * sn);
  a = bf2f(k[base + j]); b = bf2f(k[base + j + 64]);
  k[base + j]      = f2bf(a * cs - b * sn);
  k[base + j + 64] = f2bf(b * cs + a * sn);
}

// ---------- causal flash attention, block-cooperative ----------
// grid (16, 32 bh); block 256 = 4 waves; block owns 128 q rows (qb = 15-bx, long first),
// wave w owns rows [qb*128 + w*32, +32) as 2 m-tiles. KV-tile 64: K [64][128] and
// V^T [128][64] staged in LDS via global_load_lds with XOR chunk swizzle.
// P transposes through wave-private LDS slab (stride 72).
__global__ __launch_bounds__(256, 2) void flash(
    const u16* __restrict__ Q, const u16* __restrict__ Km, const u16* __restrict__ VT,
    u16* __restrict__ O)
{
  __shared__ __attribute__((aligned(16))) u16 Ks[64 * 128];    // 16 KB
  __shared__ __attribute__((aligned(16))) u16 Vs[128 * 64];    // 16 KB  (V^T: [d][kv])
  __shared__ __attribute__((aligned(16))) u16 PL[4 * 32 * 72]; // 18 KB per-wave P
  const float scale = 0.08838834764831845f;   // 1/sqrt(128)

  int bh = blockIdx.y;
  int qb = 15 - (int)blockIdx.x;
  int tid = threadIdx.x, wave = tid >> 6, lane = tid & 63;
  int quad = lane >> 4, l15 = lane & 15;
  int qw = qb * 128 + wave * 32;

  const u16* Qb = Q  + (size_t)bh * 2048 * 128;
  const u16* Kb = Km + (size_t)bh * 2048 * 128;
  const u16* Vb = VT + (size_t)bh * 2048 * 128;   // [d=128][s=2048]
  u16* PW = PL + wave * (32 * 72);

  short8 qf[2][4];
  #pragma unroll
  for (int m = 0; m < 2; m++){
    const u16* qr = Qb + (size_t)(qw + m * 16 + l15) * 128 + quad * 8;
    #pragma unroll
    for (int c = 0; c < 4; c++) qf[m][c] = *(const short8*)(qr + c * 32);
  }

  const u16* gK[4]; const u16* gV[4]; u16* lK[4]; u16* lV[4];
  #pragma unroll
  for (int r = 0; r < 4; r++){
    int ci = r * 256 + wave * 64 + lane;
    int krow = ci >> 4, kphys = ci & 15;
    int klog = kphys ^ (krow & 15);
    gK[r] = Kb + (size_t)krow * 128 + klog * 8;
    lK[r] = Ks + (size_t)(r * 256 + wave * 64) * 8;
    int vd = ci >> 3, vphys = ci & 7;
    int vlog = vphys ^ (vd & 7);
    gV[r] = Vb + (size_t)vd * 2048 + vlog * 8;
    lV[r] = Vs + (size_t)(r * 256 + wave * 64) * 8;
  }

  float mr[2][4], lr[2][4]; f32x4 o[2][8];
  #pragma unroll
  for (int m = 0; m < 2; m++)
    #pragma unroll
    for (int r = 0; r < 4; r++){ mr[m][r] = -1e30f; lr[m][r] = 0.f; }
  #pragma unroll
  for (int m = 0; m < 2; m++)
    #pragma unroll
    for (int blk = 0; blk < 8; blk++) o[m][blk] = f32x4{0.f, 0.f, 0.f, 0.f};

  int kvend = qb * 128 + 128;
  for (int k0 = 0; k0 < kvend; k0 += 64){
    __syncthreads();
    #pragma unroll
    for (int r = 0; r < 4; r++){ glds16(gK[r], lK[r]); glds16(gV[r], lV[r]); }
    #pragma unroll
    for (int r = 0; r < 4; r++){ gK[r] += 64 * 128; gV[r] += 64; }
    __syncthreads();

    int rel = qw + 31 - k0;
    if (rel >= 0){
      int smax = rel >> 4; if (smax > 3) smax = 3;
      float sreg[2][4][4];
      #pragma unroll
      for (int t = 0; t < 4; t++){
        if (t <= smax){
          short8 kf[4];
          #pragma unroll
          for (int c = 0; c < 4; c++)
            kf[c] = *(const short8*)(Ks + (t * 16 + l15) * 128 + (((c * 4 + quad) ^ l15) * 8));
          #pragma unroll
          for (int m = 0; m < 2; m++){
            f32x4 a = f32x4{0.f, 0.f, 0.f, 0.f};
            #pragma unroll
            for (int c = 0; c < 4; c++)
              a = __builtin_amdgcn_mfma_f32_16x16x32_bf16(qf[m][c], kf[c], a, 0, 0, 0);
            int kvcol = k0 + t * 16 + l15;
            #pragma unroll
            for (int r = 0; r < 4; r++){
              float v = a[r] * scale;
              int row = qw + m * 16 + quad * 4 + r;
              if (kvcol > row) v = -1e30f;
              sreg[m][t][r] = v;
            }
          }
        }
      }
      float alpha[2][4];
      #pragma unroll
      for (int m = 0; m < 2; m++){
        #pragma unroll
        for (int r = 0; r < 4; r++){
          float x = sreg[m][0][r];
          #pragma unroll
          for (int t = 1; t < 4; t++) if (t <= smax) x = fmaxf(x, sreg[m][t][r]);
          x = fmaxf(x, __shfl_xor(x, 1));
          x = fmaxf(x, __shfl_xor(x, 2));
          x = fmaxf(x, __shfl_xor(x, 4));
          x = fmaxf(x, __shfl_xor(x, 8));
          float mn = fmaxf(mr[m][r], x);
          alpha[m][r] = __expf(mr[m][r] - mn);
          mr[m][r] = mn;
        }
      }
      float lsum[2][4];
      #pragma unroll
      for (int m = 0; m < 2; m++)
        #pragma unroll
        for (int r = 0; r < 4; r++) lsum[m][r] = 0.f;
      #pragma unroll
      for (int t = 0; t < 4; t++){
        if (t <= smax){
          #pragma unroll
          for (int m = 0; m < 2; m++)
            #pragma unroll
            for (int r = 0; r < 4; r++){
              float p = __expf(sreg[m][t][r] - mr[m][r]);
              lsum[m][r] += p;
              PW[(m * 16 + quad * 4 + r) * 72 + t * 16 + l15] = f2bf(p);
            }
        }
      }
      if (!(smax & 1)){
        #pragma unroll
        for (int m = 0; m < 2; m++)
          #pragma unroll
          for (int r = 0; r < 4; r++)
            PW[(m * 16 + quad * 4 + r) * 72 + (smax + 1) * 16 + l15] = 0;
      }
      #pragma unroll
      for (int m = 0; m < 2; m++)
        #pragma unroll
        for (int r = 0; r < 4; r++){
          float sv = lsum[m][r];
          sv += __shfl_xor(sv, 1); sv += __shfl_xor(sv, 2);
          sv += __shfl_xor(sv, 4); sv += __shfl_xor(sv, 8);
          lr[m][r] = lr[m][r] * alpha[m][r] + sv;
        }
      #pragma unroll
      for (int m = 0; m < 2; m++)
        #pragma unroll
        for (int blk = 0; blk < 8; blk++){
          o[m][blk][0] *= alpha[m][0]; o[m][blk][1] *= alpha[m][1];
          o[m][blk][2] *= alpha[m][2]; o[m][blk][3] *= alpha[m][3];
        }
      __builtin_amdgcn_s_waitcnt(0xC07F);   // lgkmcnt(0): own-wave P writes visible
      int nch = (smax >> 1) + 1;
      #pragma unroll
      for (int c2 = 0; c2 < 2; c2++){
        if (c2 < nch){
          short8 pf[2];
          #pragma unroll
          for (int m = 0; m < 2; m++)
            pf[m] = *(const short8*)(PW + (m * 16 + l15) * 72 + c2 * 32 + quad * 8);
          #pragma unroll
          for (int blk = 0; blk < 8; blk++){
            int d = blk * 16 + l15;
            short8 vf = *(const short8*)(Vs + d * 64 + (((c2 * 4 + quad) ^ (l15 & 7)) * 8));
            #pragma unroll
            for (int m = 0; m < 2; m++)
              o[m][blk] = __builtin_amdgcn_mfma_f32_16x16x32_bf16(pf[m], vf, o[m][blk], 0, 0, 0);
          }
        }
      }
    }
  }

  int b = bh >> 4, h = bh & 15;
  #pragma unroll
  for (int m = 0; m < 2; m++){
    float inv[4];
    #pragma unroll
    for (int r = 0; r < 4; r++) inv[r] = 1.0f / lr[m][r];
    #pragma unroll
    for (int blk = 0; blk < 8; blk++){
      int d = h * 128 + blk * 16 + l15;
      #pragma unroll
      for (int r = 0; r < 4; r++){
        int srow = qw + m * 16 + quad * 4 + r;
        O[((size_t)(b * 2048 + srow)) * 2048 + d] = f2bf(o[m][blk][r] * inv[r]);
      }
    }
  }
}

// ---------- launcher ----------
extern "C" void kernel_launch(void* const* d_in, const int* in_sizes, int n_in,
                              void* d_out, int out_size, void* d_ws, size_t ws_size,
                              hipStream_t stream)
{
  const float* x  = (const float*)d_in[0];
  const float* Wq = (const float*)d_in[2];
  const float* bq = (const float*)d_in[3];
  const float* Wk = (const float*)d_in[4];
  const float* bk = (const float*)d_in[5];
  const float* Wv = (const float*)d_in[6];
  const float* bv = (const float*)d_in[7];
  const float* Wo = (const float*)d_in[8];
  const float* bo = (const float*)d_in[9];
  float* out = (float*)d_out;

  char* ws = (char*)d_ws;
  u16* xb   = (u16*)(ws);                    // [4096][2048]
  u16* wcat = (u16*)(ws + 16777216);         // [6144][2048] Wq|Wk|Wv (wob contiguous after)
  u16* wob  = (u16*)(ws + 41943040);         // [2048][2048]
  u16* qws  = (u16*)(ws + 50331648);         // [32][2048][128]
  u16* kws  = (u16*)(ws + 67108864);
  u16* vws  = (u16*)(ws + 83886080);         // [32][128][2048] V^T
  u16* attn = (u16*)(ws + 100663296);        // [4096][2048]

  cvt_f32_bf16<<<8192, 256, 0, stream>>>(x, xb, (2 * 2048 * 2048) / 4);
  cvt_w4<<<16384, 256, 0, stream>>>(Wq, Wk, Wv, Wo, wcat);

  gemm_bt<<<dim3(48, 32), 256, 0, stream>>>(xb, wcat, 0, qws, kws, vws,
                                            bq, bk, bv, nullptr, nullptr);
  rope_qk<<<16384, 256, 0, stream>>>(qws, kws);
  flash<<<dim3(16, 32), 256, 0, stream>>>(qws, kws, vws, attn);
  gemm_bt<<<dim3(16, 32), 256, 0, stream>>>(attn, wob, 1, nullptr, nullptr, nullptr,
                                            nullptr, nullptr, nullptr, out, bo);
}

// Round 5
// 471.508 us; speedup vs baseline: 1.2057x; 1.2057x over previous
//
#include <hip/hip_runtime.h>

typedef unsigned short u16;
typedef __attribute__((ext_vector_type(8))) short short8;
typedef __attribute__((ext_vector_type(4))) float f32x4;
typedef __attribute__((ext_vector_type(4))) unsigned short u16x4;

// ---------- bf16 helpers (OCP bf16 = raw upper 16 bits of fp32, RNE) ----------
__device__ __forceinline__ float bf2f(u16 h){
  unsigned u = ((unsigned)h) << 16; float f; __builtin_memcpy(&f, &u, 4); return f;
}
__device__ __forceinline__ u16 f2bf(float f){
  unsigned u; __builtin_memcpy(&u, &f, 4);
  unsigned r = u + 0x7fffu + ((u >> 16) & 1u);
  return (u16)(r >> 16);
}

// ---------- async global->LDS (16B per lane, wave-uniform LDS base) ----------
__device__ __forceinline__ void glds16(const u16* g, u16* l){
  __builtin_amdgcn_global_load_lds(
      (const __attribute__((address_space(1))) unsigned int*)(const void*)g,
      (__attribute__((address_space(3))) unsigned int*)(void*)l, 16, 0, 0);
}

// ---------- fused fp32 -> bf16 conversion: x (8192 blocks) + 4 weights ----------
__global__ __launch_bounds__(256) void cvt_all(const float* __restrict__ x,
    const float* __restrict__ w0, const float* __restrict__ w1,
    const float* __restrict__ w2, const float* __restrict__ w3,
    u16* __restrict__ xb, u16* __restrict__ wb){
  int blk = blockIdx.x;
  const float* src; u16* dst; int i;
  if (blk < 8192){
    src = x; dst = xb; i = blk * 256 + threadIdx.x;
  } else {
    int b2 = blk - 8192;
    int which = b2 >> 12;
    src = (which == 0) ? w0 : (which == 1) ? w1 : (which == 2) ? w2 : w3;
    dst = wb + (size_t)which * 4194304;
    i = (b2 & 4095) * 256 + threadIdx.x;
  }
  float4 f = ((const float4*)src)[i];
  u16x4 o; o.x = f2bf(f.x); o.y = f2bf(f.y); o.z = f2bf(f.z); o.w = f2bf(f.w);
  ((u16x4*)dst)[i] = o;
}

// ---------- GEMM C[M,N] = A[M,K] @ B[N,K]^T  (both bf16, K=2048, BK=32) ----------
// LDS geometry (zero-conflict, validated round 4): tile 128x32 stored as [64][64] u16,
// two k-rows per LDS row; slot = (r&1)*4 + chunk, phys = slot ^ (lrow&7).
// B-column mapping: d = wn*32 + (j>>1)*64 + (j&1)*16 + l15  -> rope pair (d,d+64) is
// (acc[i][jp], acc[i][jp+2]) in-register.
// mode 0: N=6144 (Wq|Wk|Wv); Q,K scatter+RoPE into [B,H,S,DK], V into [B,H,DK,S]^T
// mode 1: N=2048 (Wo), write fp32 out + bias
__global__ __launch_bounds__(256) void gemm_bt(
    const u16* __restrict__ A, const u16* __restrict__ Bm, int mode,
    u16* __restrict__ qws, u16* __restrict__ kws, u16* __restrict__ vws,
    const float* __restrict__ bq, const float* __restrict__ bk, const float* __restrict__ bv,
    float* __restrict__ outf, const float* __restrict__ bo)
{
  const int K = 2048;
  __shared__ __attribute__((aligned(16))) u16 As[64 * 64];   // 8 KB
  __shared__ __attribute__((aligned(16))) u16 Bs[64 * 64];   // 8 KB

  int tid = threadIdx.x, wave = tid >> 6, lane = tid & 63;
  int quad = lane >> 4, l15 = lane & 15;
  int wm = wave >> 1, wn = wave & 1;

  size_t rowA0 = (size_t)blockIdx.y * 128;
  size_t rowB0 = (size_t)blockIdx.x * 128;

  // staging: round ri (0..1), slot s = ri*256 + tid; lrow=s>>3, phys p=s&7,
  // logslot ls = p ^ (lrow&7), tile row r = lrow*2 + (ls>>2), k-chunk c = ls&3.
  const u16* gA[2]; const u16* gB[2]; u16* lA[2]; u16* lB[2];
  #pragma unroll
  for (int ri = 0; ri < 2; ri++){
    int s = ri * 256 + tid;
    int lrow = s >> 3, p = s & 7;
    int ls = p ^ (lrow & 7);
    int r = lrow * 2 + (ls >> 2);
    int c = ls & 3;
    gA[ri] = A  + (rowA0 + r) * K + c * 8;
    gB[ri] = Bm + (rowB0 + r) * K + c * 8;
    lA[ri] = As + (size_t)(ri * 256 + wave * 64) * 8;
    lB[ri] = Bs + (size_t)(ri * 256 + wave * 64) * 8;
  }

  f32x4 acc[4][4];
  #pragma unroll
  for (int i = 0; i < 4; i++)
    #pragma unroll
    for (int j = 0; j < 4; j++) acc[i][j] = f32x4{0.f, 0.f, 0.f, 0.f};

  // fragment read offsets: row ra/rb -> lrow*64 + (((row&1)*4+quad)^(lrow&7))*8
  int aoff[4], boff[4];
  #pragma unroll
  for (int t = 0; t < 4; t++){
    int ra = wm * 64 + t * 16 + l15;
    int al = ra >> 1;
    aoff[t] = al * 64 + ((((ra & 1) * 4 + quad) ^ (al & 7)) * 8);
    int rb = wn * 32 + (t >> 1) * 64 + (t & 1) * 16 + l15;
    int bl = rb >> 1;
    boff[t] = bl * 64 + ((((rb & 1) * 4 + quad) ^ (bl & 7)) * 8);
  }

  for (int k0 = 0; k0 < K; k0 += 32){
    __syncthreads();
    glds16(gA[0], lA[0]); glds16(gA[1], lA[1]);
    glds16(gB[0], lB[0]); glds16(gB[1], lB[1]);
    gA[0] += 32; gA[1] += 32; gB[0] += 32; gB[1] += 32;
    __syncthreads();
    short8 af[4], bfr[4];
    #pragma unroll
    for (int t = 0; t < 4; t++){
      af[t]  = *(const short8*)(As + aoff[t]);
      bfr[t] = *(const short8*)(Bs + boff[t]);
    }
    #pragma unroll
    for (int i = 0; i < 4; i++)
      #pragma unroll
      for (int j = 0; j < 4; j++)
        acc[i][j] = __builtin_amdgcn_mfma_f32_16x16x32_bf16(af[i], bfr[j], acc[i][j], 0, 0, 0);
  }

  // C layout per 16x16 tile: row m = quad*4 + reg, col n = l15   [verified m89]
  if (mode == 0){
    int col0 = (int)rowB0;
    int mat = col0 >> 11;                  // 0=Q 1=K 2=V
    int cm  = col0 & 2047;
    const float* bias = (mat == 0) ? bq : (mat == 1) ? bk : bv;
    int b  = (int)(rowA0 >> 11);
    int s0 = (int)(rowA0 & 2047);
    int h  = cm >> 7;
    size_t base = ((size_t)(b * 16 + h)) * 2048 * 128;
    if (mat == 2){
      // V stored TRANSPOSED: [B,H,DK,S]
      #pragma unroll
      for (int j = 0; j < 4; j++){
        int d = wn * 32 + (j >> 1) * 64 + (j & 1) * 16 + l15;
        float bv_ = bias[cm + d];
        #pragma unroll
        for (int i = 0; i < 4; i++){
          int srow = s0 + wm * 64 + i * 16 + quad * 4;
          u16x4 pk;
          #pragma unroll
          for (int r = 0; r < 4; r++) pk[r] = f2bf(acc[i][j][r] + bv_);
          *(u16x4*)(vws + base + (size_t)d * 2048 + srow) = pk;
        }
      }
    } else {
      // Q/K: fused bias + RoPE, pairs (dlow, dlow+64) = (acc[*][jp], acc[*][jp+2])
      u16* dst = (mat == 0) ? qws : kws;
      #pragma unroll
      for (int jp = 0; jp < 2; jp++){
        int dlow = wn * 32 + jp * 16 + l15;          // 0..63
        float bias_lo = bias[cm + dlow];
        float bias_hi = bias[cm + dlow + 64];
        float invf = __expf(-0.14391156831212788f * (float)dlow);  // 10000^(-dlow/64)
        #pragma unroll
        for (int i = 0; i < 4; i++){
          int srow0 = s0 + wm * 64 + i * 16 + quad * 4;
          #pragma unroll
          for (int r = 0; r < 4; r++){
            float a  = acc[i][jp][r]     + bias_lo;
            float b2 = acc[i][jp + 2][r] + bias_hi;
            float th = (float)(srow0 + r) * invf;
            float sn, cs; __sincosf(th, &sn, &cs);
            size_t ro = base + (size_t)(srow0 + r) * 128;
            dst[ro + dlow]      = f2bf(a * cs - b2 * sn);
            dst[ro + dlow + 64] = f2bf(b2 * cs + a * sn);
          }
        }
      }
    }
  } else {
    int col0 = (int)rowB0;
    #pragma unroll
    for (int j = 0; j < 4; j++){
      int c = col0 + wn * 32 + (j >> 1) * 64 + (j & 1) * 16 + l15;
      float bo_ = bo[c];
      #pragma unroll
      for (int i = 0; i < 4; i++){
        int rg = (int)rowA0 + wm * 64 + i * 16 + quad * 4;
        #pragma unroll
        for (int r = 0; r < 4; r++)
          outf[(size_t)(rg + r) * 2048 + c] = acc[i][j][r] + bo_;
      }
    }
  }
}

// ---------- causal flash attention, block-cooperative (round-3 config, unchanged) ----------
__global__ __launch_bounds__(256, 2) void flash(
    const u16* __restrict__ Q, const u16* __restrict__ Km, const u16* __restrict__ VT,
    u16* __restrict__ O)
{
  __shared__ __attribute__((aligned(16))) u16 Ks[64 * 128];    // 16 KB
  __shared__ __attribute__((aligned(16))) u16 Vs[128 * 64];    // 16 KB  (V^T: [d][kv])
  __shared__ __attribute__((aligned(16))) u16 PL[4 * 32 * 72]; // 18 KB per-wave P
  const float scale = 0.08838834764831845f;   // 1/sqrt(128)

  int bh = blockIdx.y;
  int qb = 15 - (int)blockIdx.x;
  int tid = threadIdx.x, wave = tid >> 6, lane = tid & 63;
  int quad = lane >> 4, l15 = lane & 15;
  int qw = qb * 128 + wave * 32;

  const u16* Qb = Q  + (size_t)bh * 2048 * 128;
  const u16* Kb = Km + (size_t)bh * 2048 * 128;
  const u16* Vb = VT + (size_t)bh * 2048 * 128;   // [d=128][s=2048]
  u16* PW = PL + wave * (32 * 72);

  short8 qf[2][4];
  #pragma unroll
  for (int m = 0; m < 2; m++){
    const u16* qr = Qb + (size_t)(qw + m * 16 + l15) * 128 + quad * 8;
    #pragma unroll
    for (int c = 0; c < 4; c++) qf[m][c] = *(const short8*)(qr + c * 32);
  }

  const u16* gK[4]; const u16* gV[4]; u16* lK[4]; u16* lV[4];
  #pragma unroll
  for (int r = 0; r < 4; r++){
    int ci = r * 256 + wave * 64 + lane;
    int krow = ci >> 4, kphys = ci & 15;
    int klog = kphys ^ (krow & 15);
    gK[r] = Kb + (size_t)krow * 128 + klog * 8;
    lK[r] = Ks + (size_t)(r * 256 + wave * 64) * 8;
    int vd = ci >> 3, vphys = ci & 7;
    int vlog = vphys ^ (vd & 7);
    gV[r] = Vb + (size_t)vd * 2048 + vlog * 8;
    lV[r] = Vs + (size_t)(r * 256 + wave * 64) * 8;
  }

  float mr[2][4], lr[2][4]; f32x4 o[2][8];
  #pragma unroll
  for (int m = 0; m < 2; m++)
    #pragma unroll
    for (int r = 0; r < 4; r++){ mr[m][r] = -1e30f; lr[m][r] = 0.f; }
  #pragma unroll
  for (int m = 0; m < 2; m++)
    #pragma unroll
    for (int blk = 0; blk < 8; blk++) o[m][blk] = f32x4{0.f, 0.f, 0.f, 0.f};

  int kvend = qb * 128 + 128;
  for (int k0 = 0; k0 < kvend; k0 += 64){
    __syncthreads();
    #pragma unroll
    for (int r = 0; r < 4; r++){ glds16(gK[r], lK[r]); glds16(gV[r], lV[r]); }
    #pragma unroll
    for (int r = 0; r < 4; r++){ gK[r] += 64 * 128; gV[r] += 64; }
    __syncthreads();

    int rel = qw + 31 - k0;
    if (rel >= 0){
      int smax = rel >> 4; if (smax > 3) smax = 3;
      float sreg[2][4][4];
      #pragma unroll
      for (int t = 0; t < 4; t++){
        if (t <= smax){
          short8 kf[4];
          #pragma unroll
          for (int c = 0; c < 4; c++)
            kf[c] = *(const short8*)(Ks + (t * 16 + l15) * 128 + (((c * 4 + quad) ^ l15) * 8));
          #pragma unroll
          for (int m = 0; m < 2; m++){
            f32x4 a = f32x4{0.f, 0.f, 0.f, 0.f};
            #pragma unroll
            for (int c = 0; c < 4; c++)
              a = __builtin_amdgcn_mfma_f32_16x16x32_bf16(qf[m][c], kf[c], a, 0, 0, 0);
            int kvcol = k0 + t * 16 + l15;
            #pragma unroll
            for (int r = 0; r < 4; r++){
              float v = a[r] * scale;
              int row = qw + m * 16 + quad * 4 + r;
              if (kvcol > row) v = -1e30f;
              sreg[m][t][r] = v;
            }
          }
        }
      }
      float alpha[2][4];
      #pragma unroll
      for (int m = 0; m < 2; m++){
        #pragma unroll
        for (int r = 0; r < 4; r++){
          float x = sreg[m][0][r];
          #pragma unroll
          for (int t = 1; t < 4; t++) if (t <= smax) x = fmaxf(x, sreg[m][t][r]);
          x = fmaxf(x, __shfl_xor(x, 1));
          x = fmaxf(x, __shfl_xor(x, 2));
          x = fmaxf(x, __shfl_xor(x, 4));
          x = fmaxf(x, __shfl_xor(x, 8));
          float mn = fmaxf(mr[m][r], x);
          alpha[m][r] = __expf(mr[m][r] - mn);
          mr[m][r] = mn;
        }
      }
      float lsum[2][4];
      #pragma unroll
      for (int m = 0; m < 2; m++)
        #pragma unroll
        for (int r = 0; r < 4; r++) lsum[m][r] = 0.f;
      #pragma unroll
      for (int t = 0; t < 4; t++){
        if (t <= smax){
          #pragma unroll
          for (int m = 0; m < 2; m++)
            #pragma unroll
            for (int r = 0; r < 4; r++){
              float p = __expf(sreg[m][t][r] - mr[m][r]);
              lsum[m][r] += p;
              PW[(m * 16 + quad * 4 + r) * 72 + t * 16 + l15] = f2bf(p);
            }
        }
      }
      if (!(smax & 1)){
        #pragma unroll
        for (int m = 0; m < 2; m++)
          #pragma unroll
          for (int r = 0; r < 4; r++)
            PW[(m * 16 + quad * 4 + r) * 72 + (smax + 1) * 16 + l15] = 0;
      }
      #pragma unroll
      for (int m = 0; m < 2; m++)
        #pragma unroll
        for (int r = 0; r < 4; r++){
          float sv = lsum[m][r];
          sv += __shfl_xor(sv, 1); sv += __shfl_xor(sv, 2);
          sv += __shfl_xor(sv, 4); sv += __shfl_xor(sv, 8);
          lr[m][r] = lr[m][r] * alpha[m][r] + sv;
        }
      #pragma unroll
      for (int m = 0; m < 2; m++)
        #pragma unroll
        for (int blk = 0; blk < 8; blk++){
          o[m][blk][0] *= alpha[m][0]; o[m][blk][1] *= alpha[m][1];
          o[m][blk][2] *= alpha[m][2]; o[m][blk][3] *= alpha[m][3];
        }
      __builtin_amdgcn_s_waitcnt(0xC07F);   // lgkmcnt(0): own-wave P writes visible
      int nch = (smax >> 1) + 1;
      #pragma unroll
      for (int c2 = 0; c2 < 2; c2++){
        if (c2 < nch){
          short8 pf[2];
          #pragma unroll
          for (int m = 0; m < 2; m++)
            pf[m] = *(const short8*)(PW + (m * 16 + l15) * 72 + c2 * 32 + quad * 8);
          #pragma unroll
          for (int blk = 0; blk < 8; blk++){
            int d = blk * 16 + l15;
            short8 vf = *(const short8*)(Vs + d * 64 + (((c2 * 4 + quad) ^ (l15 & 7)) * 8));
            #pragma unroll
            for (int m = 0; m < 2; m++)
              o[m][blk] = __builtin_amdgcn_mfma_f32_16x16x32_bf16(pf[m], vf, o[m][blk], 0, 0, 0);
          }
        }
      }
    }
  }

  int b = bh >> 4, h = bh & 15;
  #pragma unroll
  for (int m = 0; m < 2; m++){
    float inv[4];
    #pragma unroll
    for (int r = 0; r < 4; r++) inv[r] = 1.0f / lr[m][r];
    #pragma unroll
    for (int blk = 0; blk < 8; blk++){
      int d = h * 128 + blk * 16 + l15;
      #pragma unroll
      for (int r = 0; r < 4; r++){
        int srow = qw + m * 16 + quad * 4 + r;
        O[((size_t)(b * 2048 + srow)) * 2048 + d] = f2bf(o[m][blk][r] * inv[r]);
      }
    }
  }
}

// ---------- launcher ----------
extern "C" void kernel_launch(void* const* d_in, const int* in_sizes, int n_in,
                              void* d_out, int out_size, void* d_ws, size_t ws_size,
                              hipStream_t stream)
{
  const float* x  = (const float*)d_in[0];
  const float* Wq = (const float*)d_in[2];
  const float* bq = (const float*)d_in[3];
  const float* Wk = (const float*)d_in[4];
  const float* bk = (const float*)d_in[5];
  const float* Wv = (const float*)d_in[6];
  const float* bv = (const float*)d_in[7];
  const float* Wo = (const float*)d_in[8];
  const float* bo = (const float*)d_in[9];
  float* out = (float*)d_out;

  char* ws = (char*)d_ws;
  u16* xb   = (u16*)(ws);                    // [4096][2048]
  u16* wcat = (u16*)(ws + 16777216);         // [6144][2048] Wq|Wk|Wv, Wo contiguous after
  u16* wob  = (u16*)(ws + 41943040);         // [2048][2048]
  u16* qws  = (u16*)(ws + 50331648);         // [32][2048][128]
  u16* kws  = (u16*)(ws + 67108864);
  u16* vws  = (u16*)(ws + 83886080);         // [32][128][2048] V^T
  u16* attn = (u16*)(ws + 100663296);        // [4096][2048]

  cvt_all<<<24576, 256, 0, stream>>>(x, Wq, Wk, Wv, Wo, xb, wcat);

  gemm_bt<<<dim3(48, 32), 256, 0, stream>>>(xb, wcat, 0, qws, kws, vws,
                                            bq, bk, bv, nullptr, nullptr);
  flash<<<dim3(16, 32), 256, 0, stream>>>(qws, kws, vws, attn);
  gemm_bt<<<dim3(16, 32), 256, 0, stream>>>(attn, wob, 1, nullptr, nullptr, nullptr,
                                            nullptr, nullptr, nullptr, out, bo);
}

// Round 6
// 455.771 us; speedup vs baseline: 1.2473x; 1.0345x over previous
//
#include <hip/hip_runtime.h>

typedef unsigned short u16;
typedef __attribute__((ext_vector_type(8))) short short8;
typedef __attribute__((ext_vector_type(4))) float f32x4;
typedef __attribute__((ext_vector_type(4))) unsigned short u16x4;

// ---------- bf16 helpers (OCP bf16 = raw upper 16 bits of fp32, RNE) ----------
__device__ __forceinline__ float bf2f(u16 h){
  unsigned u = ((unsigned)h) << 16; float f; __builtin_memcpy(&f, &u, 4); return f;
}
__device__ __forceinline__ u16 f2bf(float f){
  unsigned u; __builtin_memcpy(&u, &f, 4);
  unsigned r = u + 0x7fffu + ((u >> 16) & 1u);
  return (u16)(r >> 16);
}

// ---------- async global->LDS (16B per lane, wave-uniform LDS base) ----------
__device__ __forceinline__ void glds16(const u16* g, u16* l){
  __builtin_amdgcn_global_load_lds(
      (const __attribute__((address_space(1))) unsigned int*)(const void*)g,
      (__attribute__((address_space(3))) unsigned int*)(void*)l, 16, 0, 0);
}

// ---------- fused fp32 -> bf16 conversion: x (8192 blocks) + 4 weights ----------
__global__ __launch_bounds__(256) void cvt_all(const float* __restrict__ x,
    const float* __restrict__ w0, const float* __restrict__ w1,
    const float* __restrict__ w2, const float* __restrict__ w3,
    u16* __restrict__ xb, u16* __restrict__ wb){
  int blk = blockIdx.x;
  const float* src; u16* dst; int i;
  if (blk < 8192){
    src = x; dst = xb; i = blk * 256 + threadIdx.x;
  } else {
    int b2 = blk - 8192;
    int which = b2 >> 12;
    src = (which == 0) ? w0 : (which == 1) ? w1 : (which == 2) ? w2 : w3;
    dst = wb + (size_t)which * 4194304;
    i = (b2 & 4095) * 256 + threadIdx.x;
  }
  float4 f = ((const float4*)src)[i];
  u16x4 o; o.x = f2bf(f.x); o.y = f2bf(f.y); o.z = f2bf(f.z); o.w = f2bf(f.w);
  ((u16x4*)dst)[i] = o;
}

// ---------- GEMM C[M,N] = A[M,K] @ B[N,K]^T  (both bf16, K=2048, BK=32) ----------
// (unchanged from round 5: zero-conflict LDS geometry, fused bias+RoPE epilogue)
__global__ __launch_bounds__(256) void gemm_bt(
    const u16* __restrict__ A, const u16* __restrict__ Bm, int mode,
    u16* __restrict__ qws, u16* __restrict__ kws, u16* __restrict__ vws,
    const float* __restrict__ bq, const float* __restrict__ bk, const float* __restrict__ bv,
    float* __restrict__ outf, const float* __restrict__ bo)
{
  const int K = 2048;
  __shared__ __attribute__((aligned(16))) u16 As[64 * 64];   // 8 KB
  __shared__ __attribute__((aligned(16))) u16 Bs[64 * 64];   // 8 KB

  int tid = threadIdx.x, wave = tid >> 6, lane = tid & 63;
  int quad = lane >> 4, l15 = lane & 15;
  int wm = wave >> 1, wn = wave & 1;

  size_t rowA0 = (size_t)blockIdx.y * 128;
  size_t rowB0 = (size_t)blockIdx.x * 128;

  const u16* gA[2]; const u16* gB[2]; u16* lA[2]; u16* lB[2];
  #pragma unroll
  for (int ri = 0; ri < 2; ri++){
    int s = ri * 256 + tid;
    int lrow = s >> 3, p = s & 7;
    int ls = p ^ (lrow & 7);
    int r = lrow * 2 + (ls >> 2);
    int c = ls & 3;
    gA[ri] = A  + (rowA0 + r) * K + c * 8;
    gB[ri] = Bm + (rowB0 + r) * K + c * 8;
    lA[ri] = As + (size_t)(ri * 256 + wave * 64) * 8;
    lB[ri] = Bs + (size_t)(ri * 256 + wave * 64) * 8;
  }

  f32x4 acc[4][4];
  #pragma unroll
  for (int i = 0; i < 4; i++)
    #pragma unroll
    for (int j = 0; j < 4; j++) acc[i][j] = f32x4{0.f, 0.f, 0.f, 0.f};

  int aoff[4], boff[4];
  #pragma unroll
  for (int t = 0; t < 4; t++){
    int ra = wm * 64 + t * 16 + l15;
    int al = ra >> 1;
    aoff[t] = al * 64 + ((((ra & 1) * 4 + quad) ^ (al & 7)) * 8);
    int rb = wn * 32 + (t >> 1) * 64 + (t & 1) * 16 + l15;
    int bl = rb >> 1;
    boff[t] = bl * 64 + ((((rb & 1) * 4 + quad) ^ (bl & 7)) * 8);
  }

  for (int k0 = 0; k0 < K; k0 += 32){
    __syncthreads();
    glds16(gA[0], lA[0]); glds16(gA[1], lA[1]);
    glds16(gB[0], lB[0]); glds16(gB[1], lB[1]);
    gA[0] += 32; gA[1] += 32; gB[0] += 32; gB[1] += 32;
    __syncthreads();
    short8 af[4], bfr[4];
    #pragma unroll
    for (int t = 0; t < 4; t++){
      af[t]  = *(const short8*)(As + aoff[t]);
      bfr[t] = *(const short8*)(Bs + boff[t]);
    }
    #pragma unroll
    for (int i = 0; i < 4; i++)
      #pragma unroll
      for (int j = 0; j < 4; j++)
        acc[i][j] = __builtin_amdgcn_mfma_f32_16x16x32_bf16(af[i], bfr[j], acc[i][j], 0, 0, 0);
  }

  if (mode == 0){
    int col0 = (int)rowB0;
    int mat = col0 >> 11;                  // 0=Q 1=K 2=V
    int cm  = col0 & 2047;
    const float* bias = (mat == 0) ? bq : (mat == 1) ? bk : bv;
    int b  = (int)(rowA0 >> 11);
    int s0 = (int)(rowA0 & 2047);
    int h  = cm >> 7;
    size_t base = ((size_t)(b * 16 + h)) * 2048 * 128;
    if (mat == 2){
      // V stored TRANSPOSED: [B,H,DK,S]
      #pragma unroll
      for (int j = 0; j < 4; j++){
        int d = wn * 32 + (j >> 1) * 64 + (j & 1) * 16 + l15;
        float bv_ = bias[cm + d];
        #pragma unroll
        for (int i = 0; i < 4; i++){
          int srow = s0 + wm * 64 + i * 16 + quad * 4;
          u16x4 pk;
          #pragma unroll
          for (int r = 0; r < 4; r++) pk[r] = f2bf(acc[i][j][r] + bv_);
          *(u16x4*)(vws + base + (size_t)d * 2048 + srow) = pk;
        }
      }
    } else {
      // Q/K: fused bias + RoPE, pairs (dlow, dlow+64) = (acc[*][jp], acc[*][jp+2])
      u16* dst = (mat == 0) ? qws : kws;
      #pragma unroll
      for (int jp = 0; jp < 2; jp++){
        int dlow = wn * 32 + jp * 16 + l15;          // 0..63
        float bias_lo = bias[cm + dlow];
        float bias_hi = bias[cm + dlow + 64];
        float invf = __expf(-0.14391156831212788f * (float)dlow);
        #pragma unroll
        for (int i = 0; i < 4; i++){
          int srow0 = s0 + wm * 64 + i * 16 + quad * 4;
          #pragma unroll
          for (int r = 0; r < 4; r++){
            float a  = acc[i][jp][r]     + bias_lo;
            float b2 = acc[i][jp + 2][r] + bias_hi;
            float th = (float)(srow0 + r) * invf;
            float sn, cs; __sincosf(th, &sn, &cs);
            size_t ro = base + (size_t)(srow0 + r) * 128;
            dst[ro + dlow]      = f2bf(a * cs - b2 * sn);
            dst[ro + dlow + 64] = f2bf(b2 * cs + a * sn);
          }
        }
      }
    }
  } else {
    int col0 = (int)rowB0;
    #pragma unroll
    for (int j = 0; j < 4; j++){
      int c = col0 + wn * 32 + (j >> 1) * 64 + (j & 1) * 16 + l15;
      float bo_ = bo[c];
      #pragma unroll
      for (int i = 0; i < 4; i++){
        int rg = (int)rowA0 + wm * 64 + i * 16 + quad * 4;
        #pragma unroll
        for (int r = 0; r < 4; r++)
          outf[(size_t)(rg + r) * 2048 + c] = acc[i][j][r] + bo_;
      }
    }
  }
}

// ---------- causal flash attention: balanced pairs + double-buffered staging ----------
// grid (8, 32 bh); block = 4 waves, 1 block/CU (82 KB LDS). Block pr handles q-tiles
// pr and 15-pr sequentially -> every block = exactly 34 kv-iters of 64. K/V staged
// into LDS[2] ping-pong via glds16; prefetch for iter it+1 issued right after the
// iter-it barrier so the vmcnt(0) drain at the next barrier is already satisfied.
__global__ __launch_bounds__(256) void flash(
    const u16* __restrict__ Q, const u16* __restrict__ Km, const u16* __restrict__ VT,
    u16* __restrict__ O)
{
  __shared__ __attribute__((aligned(16))) u16 Ks[2][64 * 128];  // 2x16 KB
  __shared__ __attribute__((aligned(16))) u16 Vs[2][128 * 64];  // 2x16 KB (V^T: [d][kv])
  __shared__ __attribute__((aligned(16))) u16 PL[4 * 32 * 72];  // 18 KB per-wave P
  const float scale = 0.08838834764831845f;   // 1/sqrt(128)

  int bh = blockIdx.y;
  int pr = (int)blockIdx.x;              // 0..7
  int tid = threadIdx.x, wave = tid >> 6, lane = tid & 63;
  int quad = lane >> 4, l15 = lane & 15;

  const u16* Qb = Q  + (size_t)bh * 2048 * 128;
  const u16* Kb = Km + (size_t)bh * 2048 * 128;
  const u16* Vb = VT + (size_t)bh * 2048 * 128;   // [d=128][s=2048]
  u16* PW = PL + wave * (32 * 72);

  // staging lane geometry (tile-relative)
  const u16* gKb[4]; const u16* gVb[4]; int lOff[4];
  #pragma unroll
  for (int r = 0; r < 4; r++){
    int ci = r * 256 + wave * 64 + lane;
    int krow = ci >> 4;
    int klog = (ci & 15) ^ (krow & 15);
    gKb[r] = Kb + (size_t)krow * 128 + klog * 8;   // + k0*128 per tile
    int vd = ci >> 3;
    int vlog = (ci & 7) ^ (vd & 7);
    gVb[r] = Vb + (size_t)vd * 2048 + vlog * 8;    // + k0 per tile
    lOff[r] = (r * 256 + wave * 64) * 8;
  }

  for (int phase = 0; phase < 2; phase++){
    int qtile = phase ? (15 - pr) : pr;
    int qw = qtile * 128 + wave * 32;

    short8 qf[2][4];
    #pragma unroll
    for (int m = 0; m < 2; m++){
      const u16* qr = Qb + (size_t)(qw + m * 16 + l15) * 128 + quad * 8;
      #pragma unroll
      for (int c = 0; c < 4; c++) qf[m][c] = *(const short8*)(qr + c * 32);
    }

    float mr[2][4], lr[2][4]; f32x4 o[2][8];
    #pragma unroll
    for (int m = 0; m < 2; m++)
      #pragma unroll
      for (int r = 0; r < 4; r++){ mr[m][r] = -1e30f; lr[m][r] = 0.f; }
    #pragma unroll
    for (int m = 0; m < 2; m++)
      #pragma unroll
      for (int blk = 0; blk < 8; blk++) o[m][blk] = f32x4{0.f, 0.f, 0.f, 0.f};

    int niter = (qtile + 1) * 2;

    __syncthreads();   // previous phase's reads of Ks/Vs complete before re-staging
    #pragma unroll
    for (int r = 0; r < 4; r++){
      glds16(gKb[r], Ks[0] + lOff[r]);
      glds16(gVb[r], Vs[0] + lOff[r]);
    }

    for (int it = 0; it < niter; it++){
      int k0 = it * 64;
      int buf = it & 1;
      __syncthreads();   // vmcnt(0)+barrier: buf's tile landed; all waves done w/ buf^1
      if (it + 1 < niter){
        int nb = buf ^ 1;
        #pragma unroll
        for (int r = 0; r < 4; r++){
          glds16(gKb[r] + (size_t)(k0 + 64) * 128, Ks[nb] + lOff[r]);
          glds16(gVb[r] + (k0 + 64),               Vs[nb] + lOff[r]);
        }
      }
      const u16* KsB = Ks[buf];
      const u16* VsB = Vs[buf];

      int rel = qw + 31 - k0;
      if (rel >= 0){
        int smax = rel >> 4; if (smax > 3) smax = 3;
        float sreg[2][4][4];
        #pragma unroll
        for (int t = 0; t < 4; t++){
          if (t <= smax){
            short8 kf[4];
            #pragma unroll
            for (int c = 0; c < 4; c++)
              kf[c] = *(const short8*)(KsB + (t * 16 + l15) * 128 + (((c * 4 + quad) ^ l15) * 8));
            #pragma unroll
            for (int m = 0; m < 2; m++){
              f32x4 a = f32x4{0.f, 0.f, 0.f, 0.f};
              #pragma unroll
              for (int c = 0; c < 4; c++)
                a = __builtin_amdgcn_mfma_f32_16x16x32_bf16(qf[m][c], kf[c], a, 0, 0, 0);
              int kvcol = k0 + t * 16 + l15;
              #pragma unroll
              for (int r = 0; r < 4; r++){
                float v = a[r] * scale;
                int row = qw + m * 16 + quad * 4 + r;
                if (kvcol > row) v = -1e30f;
                sreg[m][t][r] = v;
              }
            }
          }
        }
        float alpha[2][4];
        #pragma unroll
        for (int m = 0; m < 2; m++){
          #pragma unroll
          for (int r = 0; r < 4; r++){
            float x = sreg[m][0][r];
            #pragma unroll
            for (int t = 1; t < 4; t++) if (t <= smax) x = fmaxf(x, sreg[m][t][r]);
            x = fmaxf(x, __shfl_xor(x, 1));
            x = fmaxf(x, __shfl_xor(x, 2));
            x = fmaxf(x, __shfl_xor(x, 4));
            x = fmaxf(x, __shfl_xor(x, 8));
            float mn = fmaxf(mr[m][r], x);
            alpha[m][r] = __expf(mr[m][r] - mn);
            mr[m][r] = mn;
          }
        }
        float lsum[2][4];
        #pragma unroll
        for (int m = 0; m < 2; m++)
          #pragma unroll
          for (int r = 0; r < 4; r++) lsum[m][r] = 0.f;
        #pragma unroll
        for (int t = 0; t < 4; t++){
          if (t <= smax){
            #pragma unroll
            for (int m = 0; m < 2; m++)
              #pragma unroll
              for (int r = 0; r < 4; r++){
                float p = __expf(sreg[m][t][r] - mr[m][r]);
                lsum[m][r] += p;
                PW[(m * 16 + quad * 4 + r) * 72 + t * 16 + l15] = f2bf(p);
              }
          }
        }
        if (!(smax & 1)){
          #pragma unroll
          for (int m = 0; m < 2; m++)
            #pragma unroll
            for (int r = 0; r < 4; r++)
              PW[(m * 16 + quad * 4 + r) * 72 + (smax + 1) * 16 + l15] = 0;
        }
        #pragma unroll
        for (int m = 0; m < 2; m++)
          #pragma unroll
          for (int r = 0; r < 4; r++){
            float sv = lsum[m][r];
            sv += __shfl_xor(sv, 1); sv += __shfl_xor(sv, 2);
            sv += __shfl_xor(sv, 4); sv += __shfl_xor(sv, 8);
            lr[m][r] = lr[m][r] * alpha[m][r] + sv;
          }
        #pragma unroll
        for (int m = 0; m < 2; m++)
          #pragma unroll
          for (int blk = 0; blk < 8; blk++){
            o[m][blk][0] *= alpha[m][0]; o[m][blk][1] *= alpha[m][1];
            o[m][blk][2] *= alpha[m][2]; o[m][blk][3] *= alpha[m][3];
          }
        __builtin_amdgcn_s_waitcnt(0xC07F);   // lgkmcnt(0): own-wave P writes visible
        int nch = (smax >> 1) + 1;
        #pragma unroll
        for (int c2 = 0; c2 < 2; c2++){
          if (c2 < nch){
            short8 pf[2];
            #pragma unroll
            for (int m = 0; m < 2; m++)
              pf[m] = *(const short8*)(PW + (m * 16 + l15) * 72 + c2 * 32 + quad * 8);
            #pragma unroll
            for (int blk = 0; blk < 8; blk++){
              int d = blk * 16 + l15;
              short8 vf = *(const short8*)(VsB + d * 64 + (((c2 * 4 + quad) ^ (l15 & 7)) * 8));
              #pragma unroll
              for (int m = 0; m < 2; m++)
                o[m][blk] = __builtin_amdgcn_mfma_f32_16x16x32_bf16(pf[m], vf, o[m][blk], 0, 0, 0);
            }
          }
        }
      }
    }

    // phase epilogue
    int b = bh >> 4, h = bh & 15;
    #pragma unroll
    for (int m = 0; m < 2; m++){
      float inv[4];
      #pragma unroll
      for (int r = 0; r < 4; r++) inv[r] = 1.0f / lr[m][r];
      #pragma unroll
      for (int blk = 0; blk < 8; blk++){
        int d = h * 128 + blk * 16 + l15;
        #pragma unroll
        for (int r = 0; r < 4; r++){
          int srow = qw + m * 16 + quad * 4 + r;
          O[((size_t)(b * 2048 + srow)) * 2048 + d] = f2bf(o[m][blk][r] * inv[r]);
        }
      }
    }
  }
}

// ---------- launcher ----------
extern "C" void kernel_launch(void* const* d_in, const int* in_sizes, int n_in,
                              void* d_out, int out_size, void* d_ws, size_t ws_size,
                              hipStream_t stream)
{
  const float* x  = (const float*)d_in[0];
  const float* Wq = (const float*)d_in[2];
  const float* bq = (const float*)d_in[3];
  const float* Wk = (const float*)d_in[4];
  const float* bk = (const float*)d_in[5];
  const float* Wv = (const float*)d_in[6];
  const float* bv = (const float*)d_in[7];
  const float* Wo = (const float*)d_in[8];
  const float* bo = (const float*)d_in[9];
  float* out = (float*)d_out;

  char* ws = (char*)d_ws;
  u16* xb   = (u16*)(ws);                    // [4096][2048]
  u16* wcat = (u16*)(ws + 16777216);         // [6144][2048] Wq|Wk|Wv, Wo contiguous after
  u16* wob  = (u16*)(ws + 41943040);         // [2048][2048]
  u16* qws  = (u16*)(ws + 50331648);         // [32][2048][128]
  u16* kws  = (u16*)(ws + 67108864);
  u16* vws  = (u16*)(ws + 83886080);         // [32][128][2048] V^T
  u16* attn = (u16*)(ws + 100663296);        // [4096][2048]

  cvt_all<<<24576, 256, 0, stream>>>(x, Wq, Wk, Wv, Wo, xb, wcat);

  gemm_bt<<<dim3(48, 32), 256, 0, stream>>>(xb, wcat, 0, qws, kws, vws,
                                            bq, bk, bv, nullptr, nullptr);
  flash<<<dim3(8, 32), 256, 0, stream>>>(qws, kws, vws, attn);
  gemm_bt<<<dim3(16, 32), 256, 0, stream>>>(attn, wob, 1, nullptr, nullptr, nullptr,
                                            nullptr, nullptr, nullptr, out, bo);
}